// Round 10
// baseline (274.452 us; speedup 1.0000x reference)
//
#include <hip/hip_runtime.h>

// Problem constants
#define G   128
#define A   100
#define WIN 10
#define FD  16
#define H   128
#define NROWS (G*A)          // 12800
#define K1  (WIN*FD)         // 160

// LDS strides
#define SST 136   // S planes [112][SST] shorts
#define YST 136   // Y/Z planes [128][YST] shorts
#define H3ST 132  // h3 [100][H3ST] floats

typedef __attribute__((ext_vector_type(8))) short short8;
typedef __attribute__((ext_vector_type(4))) short short4v;
typedef __attribute__((ext_vector_type(4))) float floatx4;
typedef __attribute__((ext_vector_type(2))) float pf2;   // packed f32 pair

struct BfPair { short h, l; };

__device__ inline unsigned short f2bf(float f) {   // RNE fp32 -> bf16
    unsigned u = __float_as_uint(f);
    u += 0x7fff + ((u >> 16) & 1);
    return (unsigned short)(u >> 16);
}
__device__ inline float bf2f(unsigned short h) {
    return __uint_as_float(((unsigned)h) << 16);
}
__device__ inline BfPair split1(float v) {
    BfPair p;
    unsigned short hb = f2bf(v);
    p.h = (short)hb;
    p.l = (short)f2bf(v - bf2f(hb));
    return p;
}

// ---------------------------------------------------------------------------
// k_prep: pre-split W1/W2/W3 into bf16 hi/lo planes, layout [n=128][k stride 160].
// One block per (layer, n) row: writes fully coalesced, loads L2-hot gather.
// ---------------------------------------------------------------------------
__global__ __launch_bounds__(64) void k_prep(const float* __restrict__ W1,
                                             const float* __restrict__ W2,
                                             const float* __restrict__ W3,
                                             short* __restrict__ Wh,
                                             short* __restrict__ Wl) {
    const int b = blockIdx.x, t = threadIdx.x;
    const int l = b >> 7, n = b & 127;
    const int K = (l == 0) ? K1 : H;
    const float* Wsrc = (l == 0) ? W1 : (l == 1) ? W2 : W3;
    short* dh = Wh + l * 128 * 160 + n * 160;
    short* dl = Wl + l * 128 * 160 + n * 160;
    for (int k = t; k < K; k += 64) {
        BfPair p = split1(Wsrc[(size_t)k * H + n]);
        dh[k] = p.h;
        dl[k] = p.l;
    }
}

// ---------------------------------------------------------------------------
// k_mega: whole network, one block per (group, half). 1024 threads = 16 waves.
// ~16 barriers total; layer-1 A-frags direct from global; W frags preloaded.
// ---------------------------------------------------------------------------
__global__ __launch_bounds__(1024) void k_mega(
    const float* __restrict__ x,
    const short* __restrict__ Whg, const short* __restrict__ Wlg,
    const float* __restrict__ b1, const float* __restrict__ b2,
    const float* __restrict__ b3,
    const float* __restrict__ cw1, const float* __restrict__ cb1,
    const float* __restrict__ cw2, const float* __restrict__ cb2,
    float* __restrict__ out)
{
    __shared__ short Ybuf[2 * 128 * YST];   // 69632 B: Y/Z planes; adjs(f32) early
    __shared__ short Sbuf[2 * 112 * SST];   // 60928 B: S planes, later h3 (f32)
    __shared__ float wp2[64][16];           //  4096 B: conv weights, c-pair packed
    __shared__ float xcT[WIN][104];         //  4160 B
    __shared__ float invn[A];
    __shared__ float dinv[A];
    // total ~139.7 KB

    short* Yh = Ybuf;            short* Yl = Ybuf + 128 * YST;
    short* Sh = Sbuf;            short* Sl = Sbuf + 112 * SST;
    float* adjs = (float*)Ybuf;  // [100][101], dead before Y is first written
    float* h3f  = (float*)Sbuf;  // [100][H3ST], written after last S use

    const int g = blockIdx.x >> 1, half = blockIdx.x & 1;
    const int t = threadIdx.x;
    const int wvid = t >> 6, lane = t & 63;
    const int quad = lane >> 4, r16 = lane & 15;

    // ---------------- phase 0: adjacency + conv weight pack ----------------
    if (t < H) {
        int cp = t >> 1, par = t & 1;
        wp2[cp][0  + par] = cw1[3 * t];
        wp2[cp][2  + par] = cw1[3 * t + 1];
        wp2[cp][4  + par] = cw1[3 * t + 2];
        wp2[cp][6  + par] = cb1[t];
        wp2[cp][8  + par] = cw2[3 * t];
        wp2[cp][10 + par] = cw2[3 * t + 1];
        wp2[cp][12 + par] = cw2[3 * t + 2];
        wp2[cp][14 + par] = cb2[0];
    }
    for (int e = t; e < A * WIN; e += 1024) {
        int a = e / WIN, wv = e % WIN;
        xcT[wv][a] = x[((g * A + a) * WIN + wv) * FD + (FD - 1)];
    }
    __syncthreads();
    if (t < A) {
        float m = 0.f;
        #pragma unroll
        for (int wv = 0; wv < WIN; wv++) m += xcT[wv][t];
        m *= (1.0f / WIN);
        float ss = 0.f;
        #pragma unroll
        for (int wv = 0; wv < WIN; wv++) {
            float v = xcT[wv][t] - m;
            xcT[wv][t] = v;
            ss += v * v;
        }
        invn[t] = rsqrtf(ss);
    }
    __syncthreads();
    for (int e = t; e < 2500; e += 1024) {
        int ti = e / 50, tj = e % 50;
        int i0 = 2 * ti, j0v = 2 * tj;
        float d00 = 0.f, d01 = 0.f, d10 = 0.f, d11 = 0.f;
        #pragma unroll
        for (int wv = 0; wv < WIN; wv++) {
            float2 xi = *(const float2*)&xcT[wv][i0];
            float2 xj = *(const float2*)&xcT[wv][j0v];
            d00 = fmaf(xi.x, xj.x, d00); d01 = fmaf(xi.x, xj.y, d01);
            d10 = fmaf(xi.y, xj.x, d10); d11 = fmaf(xi.y, xj.y, d11);
        }
        float ii0 = invn[i0], ii1 = invn[i0 + 1];
        float ij0 = invn[j0v], ij1 = invn[j0v + 1];
        float e2 = (ti == tj) ? 1.f : 0.f;
        adjs[i0 * 101 + j0v]           = 1.f - fabsf(d00 * ii0 * ij0) + e2;
        adjs[i0 * 101 + j0v + 1]       = 1.f - fabsf(d01 * ii0 * ij1);
        adjs[(i0 + 1) * 101 + j0v]     = 1.f - fabsf(d10 * ii1 * ij0);
        adjs[(i0 + 1) * 101 + j0v + 1] = 1.f - fabsf(d11 * ii1 * ij1) + e2;
    }
    __syncthreads();
    if (t < A) {
        float s = 0.f;
        for (int j = 0; j < A; j++) s += adjs[t * 101 + j];
        dinv[t] = rsqrtf(s);
    }
    __syncthreads();
    // S planes: [m<112][k<128], zero outside 100x100 (reads adjs)
    for (int e = t; e < 112 * 64; e += 1024) {
        int m = e >> 6, k2 = (e & 63) * 2;
        float v0 = (m < A && k2 < A)     ? dinv[m] * adjs[m * 101 + k2]     * dinv[k2]     : 0.f;
        float v1 = (m < A && k2 + 1 < A) ? dinv[m] * adjs[m * 101 + k2 + 1] * dinv[k2 + 1] : 0.f;
        BfPair p0 = split1(v0), p1 = split1(v1);
        *(short2*)&Sh[m * SST + k2] = make_short2(p0.h, p1.h);
        *(short2*)&Sl[m * SST + k2] = make_short2(p0.l, p1.l);
    }
    __syncthreads();   // adjs dead; Ybuf reusable
    // zero Y planes k in [112,128) (read by phase B chunk 3, never written by A)
    for (int e = t; e < 2048; e += 1024) {
        int n = e >> 4, k = 112 + (e & 15);
        Yh[n * YST + k] = 0; Yl[n * YST + k] = 0;
    }

    // ---------------- 3 GCN layers ----------------
    const int ntA  = wvid & 7;
    const int mtlo = (wvid < 8) ? 0 : 4;
    const int mcnt = (wvid < 8) ? 4 : 3;
    const int mtB  = wvid >> 1;
    const int ntB0 = (wvid & 1) * 4;
    const short8 z8 = (short8)0;

    for (int layer = 0; layer < 3; layer++) {
        const float* bg = (layer == 0) ? b1 : (layer == 1) ? b2 : b3;
        const short* wh = Whg + layer * 128 * 160;
        const short* wl = Wlg + layer * 128 * 160;
        const int nch = (layer == 0) ? 5 : 4;   // K/32

        // preload W B-frags for the whole layer (one latency exposure)
        short8 bhx[5], blx[5];
        for (int c = 0; c < nch; c++) {
            size_t wo = (size_t)(ntA * 16 + r16) * 160 + (c << 5) + quad * 8;
            bhx[c] = *(const short8*)(wh + wo);
            blx[c] = *(const short8*)(wl + wo);
        }

        // ---- phase A: Y = X @ W ----
        floatx4 acc[4];
        #pragma unroll
        for (int i = 0; i < 4; i++) acc[i] = (floatx4)0.f;

        if (layer == 0) {
            // A-frags straight from global x (predicated; no LDS, no barriers)
            for (int c = 0; c < 5; c++) {
                const int k0 = c << 5;
                for (int mi = 0; mi < mcnt; mi++) {
                    int rm = (mtlo + mi) * 16 + r16;
                    short8 ah, al;
                    if (rm < A) {
                        const float* gp = x + (size_t)(g * A + rm) * K1 + k0 + quad * 8;
                        float4 f0 = *(const float4*)gp;
                        float4 f1 = *(const float4*)(gp + 4);
                        float v[8] = {f0.x, f0.y, f0.z, f0.w, f1.x, f1.y, f1.z, f1.w};
                        #pragma unroll
                        for (int i = 0; i < 8; i++) {
                            BfPair p = split1(v[i]);
                            ah[i] = p.h; al[i] = p.l;
                        }
                    } else { ah = z8; al = z8; }
                    acc[mi] = __builtin_amdgcn_mfma_f32_16x16x32_bf16(ah, bhx[c], acc[mi], 0, 0, 0);
                    acc[mi] = __builtin_amdgcn_mfma_f32_16x16x32_bf16(ah, blx[c], acc[mi], 0, 0, 0);
                    acc[mi] = __builtin_amdgcn_mfma_f32_16x16x32_bf16(al, bhx[c], acc[mi], 0, 0, 0);
                }
            }
            // no barrier needed: phase A read no LDS this layer
        } else {
            for (int c = 0; c < 4; c++) {
                const int k0 = c << 5;
                for (int mi = 0; mi < mcnt; mi++) {
                    int mt = mtlo + mi;
                    short8 ah = *(const short8*)&Yh[(mt * 16 + r16) * YST + k0 + quad * 8];
                    short8 al = *(const short8*)&Yl[(mt * 16 + r16) * YST + k0 + quad * 8];
                    acc[mi] = __builtin_amdgcn_mfma_f32_16x16x32_bf16(ah, bhx[c], acc[mi], 0, 0, 0);
                    acc[mi] = __builtin_amdgcn_mfma_f32_16x16x32_bf16(ah, blx[c], acc[mi], 0, 0, 0);
                    acc[mi] = __builtin_amdgcn_mfma_f32_16x16x32_bf16(al, bhx[c], acc[mi], 0, 0, 0);
                }
            }
            __syncthreads();   // all Z reads done before Y overwrites the buffer
        }

        // epilogue A: write Y planes [n][k=m]
        for (int mi = 0; mi < mcnt; mi++) {
            int mt = mtlo + mi;
            short4v yh4, yl4;
            #pragma unroll
            for (int rr = 0; rr < 4; rr++) {
                BfPair p = split1(acc[mi][rr]);
                yh4[rr] = p.h; yl4[rr] = p.l;
            }
            int off = (ntA * 16 + r16) * YST + mt * 16 + quad * 4;
            *(short4v*)&Yh[off] = yh4;
            *(short4v*)&Yl[off] = yl4;
        }
        __syncthreads();

        // ---- phase B: Z = relu(S @ Y + b) ----
        floatx4 accB[4];
        #pragma unroll
        for (int i = 0; i < 4; i++) accB[i] = (floatx4)0.f;
        if (mtB < 7) {
            #pragma unroll
            for (int c = 0; c < 4; c++) {
                const int k0 = c << 5;
                short8 ah = *(const short8*)&Sh[(mtB * 16 + r16) * SST + k0 + quad * 8];
                short8 al = *(const short8*)&Sl[(mtB * 16 + r16) * SST + k0 + quad * 8];
                #pragma unroll
                for (int j = 0; j < 4; j++) {
                    int nt = ntB0 + j;
                    short8 yh8 = *(const short8*)&Yh[(nt * 16 + r16) * YST + k0 + quad * 8];
                    short8 yl8 = *(const short8*)&Yl[(nt * 16 + r16) * YST + k0 + quad * 8];
                    accB[j] = __builtin_amdgcn_mfma_f32_16x16x32_bf16(ah, yh8, accB[j], 0, 0, 0);
                    accB[j] = __builtin_amdgcn_mfma_f32_16x16x32_bf16(ah, yl8, accB[j], 0, 0, 0);
                    accB[j] = __builtin_amdgcn_mfma_f32_16x16x32_bf16(al, yh8, accB[j], 0, 0, 0);
                }
            }
        }
        __syncthreads();   // all Y reads (and S reads for last layer) done

        if (mtB < 7) {
            #pragma unroll
            for (int j = 0; j < 4; j++) {
                int n = (ntB0 + j) * 16 + r16;
                float bv = bg[n];
                #pragma unroll
                for (int rr = 0; rr < 4; rr++) {
                    int m = mtB * 16 + quad * 4 + rr;
                    float v = fmaxf(0.f, accB[j][rr] + bv);
                    if (layer < 2) {
                        BfPair p = split1(v);
                        Yh[m * YST + n] = p.h;
                        Yl[m * YST + n] = p.l;
                    } else if (m < A) {
                        h3f[m * H3ST + n] = v;
                    }
                }
            }
        }
        __syncthreads();
    }

    // ---------------- conv: fused conv1+relu+conv2, packed c-pairs ----------
    // 8 cols/lane: 50 rows x 16 col-groups = 800 active threads.
    if (t < 800) {
        const int row = t >> 4, q = t & 15;
        const int j0 = q * 8;
        const int r = half * 50 + row;
        const float* hr = h3f + (size_t)r * H3ST;

        float hh[12];   // h[j0-2 .. j0+9], zero-padded (conv1 padding)
        if (q == 0) {
            hh[0] = 0.f; hh[1] = 0.f;
            #pragma unroll
            for (int i = 0; i < 10; i++) hh[2 + i] = hr[i];
        } else if (q == 15) {
            #pragma unroll
            for (int i = 0; i < 10; i++) hh[i] = hr[118 + i];
            hh[10] = 0.f; hh[11] = 0.f;
        } else {
            #pragma unroll
            for (int i = 0; i < 12; i++) hh[i] = hr[j0 - 2 + i];
        }
        const pf2 mlo2 = (pf2)((q == 0)  ? 0.f : 1.f);  // conv2 pad: T[-1]=0
        const pf2 mhi2 = (pf2)((q == 15) ? 0.f : 1.f);  // T[128]=0
        const pf2 zero2 = (pf2)0.f;

        pf2 accp[8];
        #pragma unroll
        for (int p = 0; p < 8; p++) accp[p] = zero2;

        #pragma unroll 2
        for (int cp = 0; cp < 64; cp++) {
            pf2 w0 = *(const pf2*)&wp2[cp][0];
            pf2 w1 = *(const pf2*)&wp2[cp][2];
            pf2 w2 = *(const pf2*)&wp2[cp][4];
            pf2 bb = *(const pf2*)&wp2[cp][6];
            pf2 v0 = *(const pf2*)&wp2[cp][8];
            pf2 v1 = *(const pf2*)&wp2[cp][10];
            pf2 v2 = *(const pf2*)&wp2[cp][12];
            pf2 tt[10];
            #pragma unroll
            for (int m = 0; m < 10; m++) {
                pf2 s = __builtin_elementwise_fma(w2, (pf2)hh[m + 2],
                        __builtin_elementwise_fma(w1, (pf2)hh[m + 1],
                        __builtin_elementwise_fma(w0, (pf2)hh[m], bb)));
                tt[m] = __builtin_elementwise_max(s, zero2);
            }
            tt[0] *= mlo2;
            tt[9] *= mhi2;
            #pragma unroll
            for (int p = 0; p < 8; p++)
                accp[p] = __builtin_elementwise_fma(v0, tt[p],
                          __builtin_elementwise_fma(v1, tt[p + 1],
                          __builtin_elementwise_fma(v2, tt[p + 2], accp[p])));
        }
        const float c2b = wp2[0][14];
        float o[8];
        #pragma unroll
        for (int p = 0; p < 8; p++) o[p] = accp[p].x + accp[p].y + c2b;
        float* op = out + ((size_t)g * A + r) * H + j0;
        *(float4*)op       = make_float4(o[0], o[1], o[2], o[3]);
        *(float4*)(op + 4) = make_float4(o[4], o[5], o[6], o[7]);
    }
}

// ---------------------------------------------------------------------------
extern "C" void kernel_launch(void* const* d_in, const int* in_sizes, int n_in,
                              void* d_out, int out_size, void* d_ws, size_t ws_size,
                              hipStream_t stream) {
    const float* x   = (const float*)d_in[0];
    const float* W1  = (const float*)d_in[1];
    const float* b1  = (const float*)d_in[2];
    const float* W2  = (const float*)d_in[3];
    const float* b2  = (const float*)d_in[4];
    const float* W3  = (const float*)d_in[5];
    const float* b3  = (const float*)d_in[6];
    const float* cw1 = (const float*)d_in[7];
    const float* cb1 = (const float*)d_in[8];
    const float* cw2 = (const float*)d_in[9];
    const float* cb2 = (const float*)d_in[10];
    float* out = (float*)d_out;

    short* Wh = (short*)d_ws;              // 3*128*160 shorts
    short* Wl = Wh + 3 * 128 * 160;

    k_prep<<<384, 64, 0, stream>>>(W1, W2, W3, Wh, Wl);
    k_mega<<<G * 2, 1024, 0, stream>>>(x, Wh, Wl, b1, b2, b3,
                                       cw1, cb1, cw2, cb2, out);
}

// Round 11
// 161.390 us; speedup vs baseline: 1.7006x; 1.7006x over previous
//
#include <hip/hip_runtime.h>

// Problem constants
#define G   128
#define A   100
#define WIN 10
#define FD  16
#define H   128
#define NROWS (G*A)          // 12800
#define K1  (WIN*FD)         // 160

// LDS strides
#define SST 136   // S planes [112][SST] shorts
#define YST 136   // Y/Z planes [128][YST] shorts
#define H3ST 132  // h3 [100][H3ST] floats

typedef __attribute__((ext_vector_type(8))) short short8;
typedef __attribute__((ext_vector_type(4))) short short4v;
typedef __attribute__((ext_vector_type(4))) float floatx4;
typedef __attribute__((ext_vector_type(2))) float pf2;   // packed f32 pair

struct BfPair { short h, l; };

__device__ inline unsigned short f2bf(float f) {   // RNE fp32 -> bf16
    unsigned u = __float_as_uint(f);
    u += 0x7fff + ((u >> 16) & 1);
    return (unsigned short)(u >> 16);
}
__device__ inline float bf2f(unsigned short h) {
    return __uint_as_float(((unsigned)h) << 16);
}
__device__ inline BfPair split1(float v) {
    BfPair p;
    unsigned short hb = f2bf(v);
    p.h = (short)hb;
    p.l = (short)f2bf(v - bf2f(hb));
    return p;
}

// ---------------------------------------------------------------------------
// k_prep: pre-split W1/W2/W3 into bf16 hi/lo planes, layout [n=128][k stride 160].
// One block per (layer, n) row: writes fully coalesced, loads L2-hot gather.
// ---------------------------------------------------------------------------
__global__ __launch_bounds__(64) void k_prep(const float* __restrict__ W1,
                                             const float* __restrict__ W2,
                                             const float* __restrict__ W3,
                                             short* __restrict__ Wh,
                                             short* __restrict__ Wl) {
    const int b = blockIdx.x, t = threadIdx.x;
    const int l = b >> 7, n = b & 127;
    const int K = (l == 0) ? K1 : H;
    const float* Wsrc = (l == 0) ? W1 : (l == 1) ? W2 : W3;
    short* dh = Wh + l * 128 * 160 + n * 160;
    short* dl = Wl + l * 128 * 160 + n * 160;
    for (int k = t; k < K; k += 64) {
        BfPair p = split1(Wsrc[(size_t)k * H + n]);
        dh[k] = p.h;
        dl[k] = p.l;
    }
}

// ---------------------------------------------------------------------------
// k_mega: whole network, one block per (group, half). 1024 threads = 16 waves.
// W B-frags loaded inline per unrolled chunk (compile-time indices only —
// round-10's dynamic-indexed preload arrays spilled to scratch: 50 MB
// WRITE_SIZE. Never index private arrays with runtime values.)
// ---------------------------------------------------------------------------
__global__ __launch_bounds__(1024) void k_mega(
    const float* __restrict__ x,
    const short* __restrict__ Whg, const short* __restrict__ Wlg,
    const float* __restrict__ b1, const float* __restrict__ b2,
    const float* __restrict__ b3,
    const float* __restrict__ cw1, const float* __restrict__ cb1,
    const float* __restrict__ cw2, const float* __restrict__ cb2,
    float* __restrict__ out)
{
    __shared__ short Ybuf[2 * 128 * YST];   // 69632 B: Y/Z planes; adjs(f32) early
    __shared__ short Sbuf[2 * 112 * SST];   // 60928 B: S planes, later h3 (f32)
    __shared__ float wp2[64][16];           //  4096 B: conv weights, c-pair packed
    __shared__ float xcT[WIN][104];         //  4160 B
    __shared__ float invn[A];
    __shared__ float dinv[A];
    // total ~139.7 KB

    short* Yh = Ybuf;            short* Yl = Ybuf + 128 * YST;
    short* Sh = Sbuf;            short* Sl = Sbuf + 112 * SST;
    float* adjs = (float*)Ybuf;  // [100][101], dead before Y is first written
    float* h3f  = (float*)Sbuf;  // [100][H3ST], written after last S use

    const int g = blockIdx.x >> 1, half = blockIdx.x & 1;
    const int t = threadIdx.x;
    const int wvid = t >> 6, lane = t & 63;
    const int quad = lane >> 4, r16 = lane & 15;

    // ---------------- phase 0: adjacency + conv weight pack ----------------
    if (t < H) {
        int cp = t >> 1, par = t & 1;
        wp2[cp][0  + par] = cw1[3 * t];
        wp2[cp][2  + par] = cw1[3 * t + 1];
        wp2[cp][4  + par] = cw1[3 * t + 2];
        wp2[cp][6  + par] = cb1[t];
        wp2[cp][8  + par] = cw2[3 * t];
        wp2[cp][10 + par] = cw2[3 * t + 1];
        wp2[cp][12 + par] = cw2[3 * t + 2];
        wp2[cp][14 + par] = cb2[0];
    }
    for (int e = t; e < A * WIN; e += 1024) {
        int a = e / WIN, wv = e % WIN;
        xcT[wv][a] = x[((g * A + a) * WIN + wv) * FD + (FD - 1)];
    }
    __syncthreads();
    if (t < A) {
        float m = 0.f;
        #pragma unroll
        for (int wv = 0; wv < WIN; wv++) m += xcT[wv][t];
        m *= (1.0f / WIN);
        float ss = 0.f;
        #pragma unroll
        for (int wv = 0; wv < WIN; wv++) {
            float v = xcT[wv][t] - m;
            xcT[wv][t] = v;
            ss += v * v;
        }
        invn[t] = rsqrtf(ss);
    }
    __syncthreads();
    for (int e = t; e < 2500; e += 1024) {
        int ti = e / 50, tj = e % 50;
        int i0 = 2 * ti, j0v = 2 * tj;
        float d00 = 0.f, d01 = 0.f, d10 = 0.f, d11 = 0.f;
        #pragma unroll
        for (int wv = 0; wv < WIN; wv++) {
            float2 xi = *(const float2*)&xcT[wv][i0];
            float2 xj = *(const float2*)&xcT[wv][j0v];
            d00 = fmaf(xi.x, xj.x, d00); d01 = fmaf(xi.x, xj.y, d01);
            d10 = fmaf(xi.y, xj.x, d10); d11 = fmaf(xi.y, xj.y, d11);
        }
        float ii0 = invn[i0], ii1 = invn[i0 + 1];
        float ij0 = invn[j0v], ij1 = invn[j0v + 1];
        float e2 = (ti == tj) ? 1.f : 0.f;
        adjs[i0 * 101 + j0v]           = 1.f - fabsf(d00 * ii0 * ij0) + e2;
        adjs[i0 * 101 + j0v + 1]       = 1.f - fabsf(d01 * ii0 * ij1);
        adjs[(i0 + 1) * 101 + j0v]     = 1.f - fabsf(d10 * ii1 * ij0);
        adjs[(i0 + 1) * 101 + j0v + 1] = 1.f - fabsf(d11 * ii1 * ij1) + e2;
    }
    __syncthreads();
    if (t < A) {
        float s = 0.f;
        for (int j = 0; j < A; j++) s += adjs[t * 101 + j];
        dinv[t] = rsqrtf(s);
    }
    __syncthreads();
    // S planes: [m<112][k<128], zero outside 100x100 (reads adjs)
    for (int e = t; e < 112 * 64; e += 1024) {
        int m = e >> 6, k2 = (e & 63) * 2;
        float v0 = (m < A && k2 < A)     ? dinv[m] * adjs[m * 101 + k2]     * dinv[k2]     : 0.f;
        float v1 = (m < A && k2 + 1 < A) ? dinv[m] * adjs[m * 101 + k2 + 1] * dinv[k2 + 1] : 0.f;
        BfPair p0 = split1(v0), p1 = split1(v1);
        *(short2*)&Sh[m * SST + k2] = make_short2(p0.h, p1.h);
        *(short2*)&Sl[m * SST + k2] = make_short2(p0.l, p1.l);
    }
    __syncthreads();   // adjs dead; Ybuf reusable
    // zero Y planes k in [112,128) (read by phase B chunk 3, never written by A)
    for (int e = t; e < 2048; e += 1024) {
        int n = e >> 4, k = 112 + (e & 15);
        Yh[n * YST + k] = 0; Yl[n * YST + k] = 0;
    }

    // ---------------- 3 GCN layers ----------------
    const int ntA  = wvid & 7;
    const int mtlo = (wvid < 8) ? 0 : 4;
    const int mcnt = (wvid < 8) ? 4 : 3;
    const int mtB  = wvid >> 1;
    const int ntB0 = (wvid & 1) * 4;
    const short8 z8 = (short8)0;
    const size_t wrow = (size_t)(ntA * 16 + r16) * 160 + quad * 8;

    floatx4 acc[4];

    for (int layer = 0; layer < 3; layer++) {
        const float* bg = (layer == 0) ? b1 : (layer == 1) ? b2 : b3;
        const short* wh = Whg + layer * 128 * 160;
        const short* wl = Wlg + layer * 128 * 160;

        // ---- phase A: Y = X @ W ----
        #pragma unroll
        for (int i = 0; i < 4; i++) acc[i] = (floatx4)0.f;

        if (layer == 0) {
            // A-frags straight from global x (predicated; no LDS, no barriers)
            #pragma unroll
            for (int c = 0; c < 5; c++) {
                const int k0 = c << 5;
                short8 bh = *(const short8*)(wh + wrow + k0);
                short8 bl = *(const short8*)(wl + wrow + k0);
                #pragma unroll
                for (int mi = 0; mi < 4; mi++) {
                    if (mi >= mcnt) break;
                    int rm = (mtlo + mi) * 16 + r16;
                    short8 ah, al;
                    if (rm < A) {
                        const float* gp = x + (size_t)(g * A + rm) * K1 + k0 + quad * 8;
                        float4 f0 = *(const float4*)gp;
                        float4 f1 = *(const float4*)(gp + 4);
                        float v[8] = {f0.x, f0.y, f0.z, f0.w, f1.x, f1.y, f1.z, f1.w};
                        #pragma unroll
                        for (int i = 0; i < 8; i++) {
                            BfPair p = split1(v[i]);
                            ah[i] = p.h; al[i] = p.l;
                        }
                    } else { ah = z8; al = z8; }
                    acc[mi] = __builtin_amdgcn_mfma_f32_16x16x32_bf16(ah, bh, acc[mi], 0, 0, 0);
                    acc[mi] = __builtin_amdgcn_mfma_f32_16x16x32_bf16(ah, bl, acc[mi], 0, 0, 0);
                    acc[mi] = __builtin_amdgcn_mfma_f32_16x16x32_bf16(al, bh, acc[mi], 0, 0, 0);
                }
            }
            // no barrier needed: phase A read no LDS this layer
        } else {
            #pragma unroll
            for (int c = 0; c < 4; c++) {
                const int k0 = c << 5;
                short8 bh = *(const short8*)(wh + wrow + k0);
                short8 bl = *(const short8*)(wl + wrow + k0);
                #pragma unroll
                for (int mi = 0; mi < 4; mi++) {
                    if (mi >= mcnt) break;
                    int mt = mtlo + mi;
                    short8 ah = *(const short8*)&Yh[(mt * 16 + r16) * YST + k0 + quad * 8];
                    short8 al = *(const short8*)&Yl[(mt * 16 + r16) * YST + k0 + quad * 8];
                    acc[mi] = __builtin_amdgcn_mfma_f32_16x16x32_bf16(ah, bh, acc[mi], 0, 0, 0);
                    acc[mi] = __builtin_amdgcn_mfma_f32_16x16x32_bf16(ah, bl, acc[mi], 0, 0, 0);
                    acc[mi] = __builtin_amdgcn_mfma_f32_16x16x32_bf16(al, bh, acc[mi], 0, 0, 0);
                }
            }
            __syncthreads();   // all Z reads done before Y overwrites the buffer
        }

        // epilogue A: write Y planes [n][k=m]
        #pragma unroll
        for (int mi = 0; mi < 4; mi++) {
            if (mi >= mcnt) break;
            int mt = mtlo + mi;
            short4v yh4, yl4;
            #pragma unroll
            for (int rr = 0; rr < 4; rr++) {
                BfPair p = split1(acc[mi][rr]);
                yh4[rr] = p.h; yl4[rr] = p.l;
            }
            int off = (ntA * 16 + r16) * YST + mt * 16 + quad * 4;
            *(short4v*)&Yh[off] = yh4;
            *(short4v*)&Yl[off] = yl4;
        }
        __syncthreads();

        // ---- phase B: Z = relu(S @ Y + b) ----
        floatx4 accB[4];
        #pragma unroll
        for (int i = 0; i < 4; i++) accB[i] = (floatx4)0.f;
        if (mtB < 7) {
            #pragma unroll
            for (int c = 0; c < 4; c++) {
                const int k0 = c << 5;
                short8 ah = *(const short8*)&Sh[(mtB * 16 + r16) * SST + k0 + quad * 8];
                short8 al = *(const short8*)&Sl[(mtB * 16 + r16) * SST + k0 + quad * 8];
                #pragma unroll
                for (int j = 0; j < 4; j++) {
                    int nt = ntB0 + j;
                    short8 yh8 = *(const short8*)&Yh[(nt * 16 + r16) * YST + k0 + quad * 8];
                    short8 yl8 = *(const short8*)&Yl[(nt * 16 + r16) * YST + k0 + quad * 8];
                    accB[j] = __builtin_amdgcn_mfma_f32_16x16x32_bf16(ah, yh8, accB[j], 0, 0, 0);
                    accB[j] = __builtin_amdgcn_mfma_f32_16x16x32_bf16(ah, yl8, accB[j], 0, 0, 0);
                    accB[j] = __builtin_amdgcn_mfma_f32_16x16x32_bf16(al, yh8, accB[j], 0, 0, 0);
                }
            }
        }
        __syncthreads();   // all Y reads (and S reads for last layer) done

        if (mtB < 7) {
            #pragma unroll
            for (int j = 0; j < 4; j++) {
                int n = (ntB0 + j) * 16 + r16;
                float bv = bg[n];
                #pragma unroll
                for (int rr = 0; rr < 4; rr++) {
                    int m = mtB * 16 + quad * 4 + rr;
                    float v = fmaxf(0.f, accB[j][rr] + bv);
                    if (layer < 2) {
                        BfPair p = split1(v);
                        Yh[m * YST + n] = p.h;
                        Yl[m * YST + n] = p.l;
                    } else if (m < A) {
                        h3f[m * H3ST + n] = v;
                    }
                }
            }
        }
        __syncthreads();
    }

    // ---------------- conv: fused conv1+relu+conv2, packed c-pairs ----------
    // 8 cols/lane: 50 rows x 16 col-groups = 800 active threads.
    if (t < 800) {
        const int row = t >> 4, q = t & 15;
        const int j0 = q * 8;
        const int r = half * 50 + row;
        const float* hr = h3f + (size_t)r * H3ST;

        float hh[12];   // h[j0-2 .. j0+9], zero-padded (conv1 padding)
        if (q == 0) {
            hh[0] = 0.f; hh[1] = 0.f;
            #pragma unroll
            for (int i = 0; i < 10; i++) hh[2 + i] = hr[i];
        } else if (q == 15) {
            #pragma unroll
            for (int i = 0; i < 10; i++) hh[i] = hr[118 + i];
            hh[10] = 0.f; hh[11] = 0.f;
        } else {
            #pragma unroll
            for (int i = 0; i < 12; i++) hh[i] = hr[j0 - 2 + i];
        }
        const pf2 mlo2 = (pf2)((q == 0)  ? 0.f : 1.f);  // conv2 pad: T[-1]=0
        const pf2 mhi2 = (pf2)((q == 15) ? 0.f : 1.f);  // T[128]=0
        const pf2 zero2 = (pf2)0.f;

        pf2 accp[8];
        #pragma unroll
        for (int p = 0; p < 8; p++) accp[p] = zero2;

        #pragma unroll 2
        for (int cp = 0; cp < 64; cp++) {
            pf2 w0 = *(const pf2*)&wp2[cp][0];
            pf2 w1 = *(const pf2*)&wp2[cp][2];
            pf2 w2 = *(const pf2*)&wp2[cp][4];
            pf2 bb = *(const pf2*)&wp2[cp][6];
            pf2 v0 = *(const pf2*)&wp2[cp][8];
            pf2 v1 = *(const pf2*)&wp2[cp][10];
            pf2 v2 = *(const pf2*)&wp2[cp][12];
            pf2 tt[10];
            #pragma unroll
            for (int m = 0; m < 10; m++) {
                pf2 s = __builtin_elementwise_fma(w2, (pf2)hh[m + 2],
                        __builtin_elementwise_fma(w1, (pf2)hh[m + 1],
                        __builtin_elementwise_fma(w0, (pf2)hh[m], bb)));
                tt[m] = __builtin_elementwise_max(s, zero2);
            }
            tt[0] *= mlo2;
            tt[9] *= mhi2;
            #pragma unroll
            for (int p = 0; p < 8; p++)
                accp[p] = __builtin_elementwise_fma(v0, tt[p],
                          __builtin_elementwise_fma(v1, tt[p + 1],
                          __builtin_elementwise_fma(v2, tt[p + 2], accp[p])));
        }
        const float c2b = wp2[0][14];
        float o[8];
        #pragma unroll
        for (int p = 0; p < 8; p++) o[p] = accp[p].x + accp[p].y + c2b;
        float* op = out + ((size_t)g * A + r) * H + j0;
        *(float4*)op       = make_float4(o[0], o[1], o[2], o[3]);
        *(float4*)(op + 4) = make_float4(o[4], o[5], o[6], o[7]);
    }
}

// ---------------------------------------------------------------------------
extern "C" void kernel_launch(void* const* d_in, const int* in_sizes, int n_in,
                              void* d_out, int out_size, void* d_ws, size_t ws_size,
                              hipStream_t stream) {
    const float* x   = (const float*)d_in[0];
    const float* W1  = (const float*)d_in[1];
    const float* b1  = (const float*)d_in[2];
    const float* W2  = (const float*)d_in[3];
    const float* b2  = (const float*)d_in[4];
    const float* W3  = (const float*)d_in[5];
    const float* b3  = (const float*)d_in[6];
    const float* cw1 = (const float*)d_in[7];
    const float* cb1 = (const float*)d_in[8];
    const float* cw2 = (const float*)d_in[9];
    const float* cb2 = (const float*)d_in[10];
    float* out = (float*)d_out;

    short* Wh = (short*)d_ws;              // 3*128*160 shorts
    short* Wl = Wh + 3 * 128 * 160;

    k_prep<<<384, 64, 0, stream>>>(W1, W2, W3, Wh, Wl);
    k_mega<<<G * 2, 1024, 0, stream>>>(x, Wh, Wl, b1, b2, b3,
                                       cw1, cb1, cw2, cb2, out);
}